// Round 5
// baseline (469.105 us; speedup 1.0000x reference)
//
#include <hip/hip_runtime.h>
#include <hip/hip_bf16.h>

using bf16_t = __bf16;
using bf16x8 = __attribute__((ext_vector_type(8))) __bf16;
using bf16x4 = __attribute__((ext_vector_type(4))) __bf16;
using bf16x2 = __attribute__((ext_vector_type(2))) __bf16;
using f32x4  = __attribute__((ext_vector_type(4))) float;

#define S_  2048
#define D_  1024

typedef __attribute__((address_space(1))) unsigned int glb_u32;
typedef __attribute__((address_space(3))) unsigned int lds_u32;

__device__ __forceinline__ void async_cp16(const void* g, void* lds) {
    __builtin_amdgcn_global_load_lds(
        (glb_u32*)(unsigned long long)g,
        (lds_u32*)(unsigned int)(unsigned long long)lds,
        16, 0, 0);
}

// ---------------- weights f32 -> bf16 ----------------
__global__ __launch_bounds__(256) void cast4_f32_bf16(const float* __restrict__ a, const float* __restrict__ b,
                                                      const float* __restrict__ c, const float* __restrict__ dd,
                                                      bf16_t* __restrict__ oa, bf16_t* __restrict__ ob,
                                                      bf16_t* __restrict__ oc, bf16_t* __restrict__ od, int n4) {
    int i = blockIdx.x * 256 + threadIdx.x;
    if (i >= n4) return;
    const float* s; bf16_t* d;
    int w = blockIdx.y;
    if      (w == 0) { s = a;  d = oa; }
    else if (w == 1) { s = b;  d = ob; }
    else if (w == 2) { s = c;  d = oc; }
    else             { s = dd; d = od; }
    float4 f = reinterpret_cast<const float4*>(s)[i];
    bf16x4 o;
    o[0] = (bf16_t)f.x; o[1] = (bf16_t)f.y; o[2] = (bf16_t)f.z; o[3] = (bf16_t)f.w;
    reinterpret_cast<bf16x4*>(d)[i] = o;
}

// ---------------- fused QKV projection GEMM ----------------
// z selects (A_f32, W_bf16, output): z=0 Q (scale cs, bf16 row-major),
// z=1 K (bf16 row-major), z=2 V (bf16 transposed into per-head Vt).
// A staged from f32 global via VGPR cvt (cast fused); B staged async bf16.
__global__ __launch_bounds__(256) void gemm_qkv(const float* __restrict__ Aq, const float* __restrict__ Ak,
                                                const float* __restrict__ Av,
                                                const bf16_t* __restrict__ Wqb, const bf16_t* __restrict__ Wkb,
                                                const bf16_t* __restrict__ Wvb,
                                                bf16_t* __restrict__ Qp, bf16_t* __restrict__ Kp,
                                                bf16_t* __restrict__ Vt, float cs) {
    __shared__ bf16_t As[128 * 32];
    __shared__ bf16_t Bs[128 * 32];
    const int K = 1024;
    int tid  = threadIdx.x;
    int lane = tid & 63, w = tid >> 6;
    int l15  = lane & 15, quad = lane >> 4;
    int z = blockIdx.z;
    const float*  A  = (z == 0) ? Aq  : (z == 1) ? Ak  : Av;
    const bf16_t* Bt = (z == 0) ? Wqb : (z == 1) ? Wkb : Wvb;
    int m0 = blockIdx.y * 128, n0 = blockIdx.x * 128;
    int wm = (w >> 1) * 64, wn = (w & 1) * 64;

    int arow = tid >> 2, acol = (tid & 3) * 8;
    const float*  Ag = A  + (size_t)(m0 + arow) * K + acol;
    const bf16_t* Bg = Bt + (size_t)(n0 + (tid >> 2)) * K + (tid & 3) * 8;
    bf16_t* Bsw = Bs + tid * 8;

    f32x4 acc[4][4] = {};

    for (int k0 = 0; k0 < K; k0 += 32) {
        __syncthreads();
        async_cp16(Bg + k0,                  Bsw);
        async_cp16(Bg + k0 + (size_t)64 * K, Bsw + 2048);
        float4 a0 = *reinterpret_cast<const float4*>(Ag + k0);
        float4 a1 = *reinterpret_cast<const float4*>(Ag + k0 + 4);
        float4 a2 = *reinterpret_cast<const float4*>(Ag + k0 + (size_t)64 * K);
        float4 a3 = *reinterpret_cast<const float4*>(Ag + k0 + (size_t)64 * K + 4);
        bf16x8 v0, v1;
        v0[0]=(bf16_t)a0.x; v0[1]=(bf16_t)a0.y; v0[2]=(bf16_t)a0.z; v0[3]=(bf16_t)a0.w;
        v0[4]=(bf16_t)a1.x; v0[5]=(bf16_t)a1.y; v0[6]=(bf16_t)a1.z; v0[7]=(bf16_t)a1.w;
        v1[0]=(bf16_t)a2.x; v1[1]=(bf16_t)a2.y; v1[2]=(bf16_t)a2.z; v1[3]=(bf16_t)a2.w;
        v1[4]=(bf16_t)a3.x; v1[5]=(bf16_t)a3.y; v1[6]=(bf16_t)a3.z; v1[7]=(bf16_t)a3.w;
        *reinterpret_cast<bf16x8*>(&As[arow * 32 + acol])        = v0;
        *reinterpret_cast<bf16x8*>(&As[(arow + 64) * 32 + acol]) = v1;
        __syncthreads();
        bf16x8 af[4], bfr[4];
#pragma unroll
        for (int t = 0; t < 4; t++) {
            af[t]  = *reinterpret_cast<const bf16x8*>(&As[(wm + t * 16 + l15) * 32 + quad * 8]);
            bfr[t] = *reinterpret_cast<const bf16x8*>(&Bs[(wn + t * 16 + l15) * 32 + quad * 8]);
        }
#pragma unroll
        for (int mt = 0; mt < 4; mt++)
#pragma unroll
            for (int nt = 0; nt < 4; nt++)
                acc[mt][nt] = __builtin_amdgcn_mfma_f32_16x16x32_bf16(af[mt], bfr[nt], acc[mt][nt], 0, 0, 0);
    }

    if (z == 2) {
        // transposed epilogue into per-head V^T: Vt[((m>>11)*16 + (n>>6))*64 + (n&63)][m&2047]
#pragma unroll
        for (int mt = 0; mt < 4; mt++)
#pragma unroll
            for (int nt = 0; nt < 4; nt++) {
                int m = m0 + wm + mt * 16 + quad * 4;
                int n = n0 + wn + nt * 16 + l15;
                bf16x4 o4;
#pragma unroll
                for (int r = 0; r < 4; r++) o4[r] = (bf16_t)acc[mt][nt][r];
                size_t vrow = (size_t)((m >> 11) * 16 + (n >> 6)) * 64 + (n & 63);
                *reinterpret_cast<bf16x4*>(&Vt[vrow * S_ + (m & 2047)]) = o4;
            }
    } else {
        bf16_t* C = z ? Kp : Qp;
        float scale = z ? 1.0f : cs;
#pragma unroll
        for (int mt = 0; mt < 4; mt++)
#pragma unroll
            for (int nt = 0; nt < 4; nt++)
#pragma unroll
                for (int r = 0; r < 4; r++) {
                    int m = m0 + wm + mt * 16 + quad * 4 + r;
                    int n = n0 + wn + nt * 16 + l15;
                    C[(size_t)m * 1024 + n] = (bf16_t)(acc[mt][nt][r] * scale);
                }
    }
}

// ---------------- out-projection GEMM (bf16 A/B, f32 out) ----------------
__global__ __launch_bounds__(256) void gemm_out(const bf16_t* __restrict__ A,
                                                const bf16_t* __restrict__ Bt,
                                                float* __restrict__ C) {
    __shared__ bf16_t As[128 * 32];
    __shared__ bf16_t Bs[128 * 32];
    const int K = 1024;
    int tid  = threadIdx.x;
    int lane = tid & 63, w = tid >> 6;
    int l15  = lane & 15, quad = lane >> 4;
    int m0 = blockIdx.y * 128, n0 = blockIdx.x * 128;
    int wm = (w >> 1) * 64, wn = (w & 1) * 64;

    const bf16_t* Ag = A  + (size_t)(m0 + (tid >> 2)) * K + (tid & 3) * 8;
    const bf16_t* Bg = Bt + (size_t)(n0 + (tid >> 2)) * K + (tid & 3) * 8;
    bf16_t* Asw = As + tid * 8;
    bf16_t* Bsw = Bs + tid * 8;

    f32x4 acc[4][4] = {};

    for (int k0 = 0; k0 < K; k0 += 32) {
        __syncthreads();
        async_cp16(Ag + k0,                    Asw);
        async_cp16(Ag + k0 + (size_t)64 * K,   Asw + 2048);
        async_cp16(Bg + k0,                    Bsw);
        async_cp16(Bg + k0 + (size_t)64 * K,   Bsw + 2048);
        __syncthreads();
        bf16x8 af[4], bfr[4];
#pragma unroll
        for (int t = 0; t < 4; t++) {
            af[t]  = *reinterpret_cast<const bf16x8*>(&As[(wm + t * 16 + l15) * 32 + quad * 8]);
            bfr[t] = *reinterpret_cast<const bf16x8*>(&Bs[(wn + t * 16 + l15) * 32 + quad * 8]);
        }
#pragma unroll
        for (int mt = 0; mt < 4; mt++)
#pragma unroll
            for (int nt = 0; nt < 4; nt++)
                acc[mt][nt] = __builtin_amdgcn_mfma_f32_16x16x32_bf16(af[mt], bfr[nt], acc[mt][nt], 0, 0, 0);
    }

#pragma unroll
    for (int mt = 0; mt < 4; mt++)
#pragma unroll
        for (int nt = 0; nt < 4; nt++)
#pragma unroll
            for (int r = 0; r < 4; r++) {
                int m = m0 + wm + mt * 16 + quad * 4 + r;
                int n = n0 + wn + nt * 16 + l15;
                C[(size_t)m * 1024 + n] = acc[mt][nt][r];
            }
}

// ---------------- fused masked attention ----------------
// Transposed-S (St = K Q^T feeds O^T = V^T P^T from registers), max-free exp2
// softmax (scale baked into Q). Slim LDS (16.9 KB): Q frags loaded straight
// from global (read once), epilogue transpose buffer unioned over Ks/Vs.
__global__ __launch_bounds__(256, 5) void attn_fused(const bf16_t* __restrict__ Qp,
                                                     const bf16_t* __restrict__ Kp,
                                                     const bf16_t* __restrict__ Vt,
                                                     const int* __restrict__ vlen_p,
                                                     bf16_t* __restrict__ Out) {
    __shared__ bf16_t lds[8448];
    bf16_t* Ks = lds;          // [2][64][32] = 4096 elems
    bf16_t* Vs = lds + 4096;   // [64][68]    = 4352 elems (stride 68: conflict-free b64)
    bf16_t* T  = lds;          // epilogue reuse: [128][64] = 8192 elems

    int tid  = threadIdx.x;
    int lane = tid & 63, w = tid >> 6;
    int l15  = lane & 15, quad = lane >> 4;
    int qblk = blockIdx.x;
    int bh = blockIdx.y, b = bh >> 4, h = bh & 15;
    int vlen = vlen_p[b];
    int nkb  = (vlen + 63) >> 6;

    const bf16_t* Qg = Qp + (size_t)(b * S_ + qblk * 128) * D_ + h * 64;
    const bf16_t* Kg = Kp + (size_t)b * S_ * D_ + h * 64;
    const bf16_t* Vg = Vt + (size_t)bh * 64 * S_;

    // Q fragments straight from global (one-time)
    bf16x8 qf[2][2];
#pragma unroll
    for (int qt = 0; qt < 2; qt++)
#pragma unroll
        for (int kk = 0; kk < 2; kk++)
            qf[qt][kk] = *reinterpret_cast<const bf16x8*>(
                &Qg[(size_t)(w * 32 + qt * 16 + l15) * D_ + kk * 32 + quad * 8]);

    f32x4 o[2][4] = {};
    float l_st[2] = {0.f, 0.f};

    for (int kb = 0; kb < nkb; kb++) {
        __syncthreads();
#pragma unroll
        for (int j = 0; j < 2; j++) {
            int linear = j * 256 + tid;
            int kk = linear >> 8, row = (linear >> 2) & 63, sub = linear & 3;
            async_cp16(Kg + (size_t)(kb * 64 + row) * D_ + kk * 32 + sub * 8, Ks + linear * 8);
        }
#pragma unroll
        for (int j = 0; j < 2; j++) {
            int linear = j * 256 + tid;
            int row = linear >> 3, c8 = linear & 7;
            uint4 vv = *reinterpret_cast<const uint4*>(&Vg[(size_t)row * S_ + kb * 64 + c8 * 8]);
            uint2* vp = reinterpret_cast<uint2*>(&Vs[row * 68 + c8 * 8]);
            vp[0] = make_uint2(vv.x, vv.y);
            vp[1] = make_uint2(vv.z, vv.w);
        }
        __syncthreads();

        // St = K Q^T, both q-tiles sharing K fragments
        f32x4 sc[2][4] = {};
#pragma unroll
        for (int nt = 0; nt < 4; nt++)
#pragma unroll
            for (int kk = 0; kk < 2; kk++) {
                bf16x8 kf = *reinterpret_cast<const bf16x8*>(&Ks[kk * 2048 + (nt * 16 + l15) * 32 + quad * 8]);
                sc[0][nt] = __builtin_amdgcn_mfma_f32_16x16x32_bf16(kf, qf[0][kk], sc[0][nt], 0, 0, 0);
                sc[1][nt] = __builtin_amdgcn_mfma_f32_16x16x32_bf16(kf, qf[1][kk], sc[1][nt], 0, 0, 0);
            }

        // max-free softmax: p = exp2(st); per-lane l accumulation
        bool partial = (vlen & 63) && (kb == nkb - 1);
        bf16x8 pf[2][2];
        if (!partial) {
#pragma unroll
            for (int qt = 0; qt < 2; qt++) {
                float lacc = 0.f;
#pragma unroll
                for (int nt = 0; nt < 4; nt++)
#pragma unroll
                    for (int r = 0; r < 4; r++) {
                        float p = __builtin_exp2f(sc[qt][nt][r]);
                        lacc += p;
                        pf[qt][nt >> 1][(nt & 1) * 4 + r] = (bf16_t)p;
                    }
                l_st[qt] += lacc;
            }
        } else {
#pragma unroll
            for (int qt = 0; qt < 2; qt++) {
                float lacc = 0.f;
#pragma unroll
                for (int nt = 0; nt < 4; nt++)
#pragma unroll
                    for (int r = 0; r < 4; r++) {
                        float p = __builtin_exp2f(sc[qt][nt][r]);
                        if (kb * 64 + nt * 16 + quad * 4 + r >= vlen) p = 0.f;
                        lacc += p;
                        pf[qt][nt >> 1][(nt & 1) * 4 + r] = (bf16_t)p;
                    }
                l_st[qt] += lacc;
            }
        }

        // O^T += V^T P^T ; V^T A-fragments via conflict-free b64 pairs
#pragma unroll
        for (int np = 0; np < 2; np++)
#pragma unroll
            for (int dt = 0; dt < 4; dt++) {
                bf16x4 v0 = *reinterpret_cast<const bf16x4*>(&Vs[(dt * 16 + l15) * 68 + np * 32 + quad * 4]);
                bf16x4 v1 = *reinterpret_cast<const bf16x4*>(&Vs[(dt * 16 + l15) * 68 + np * 32 + 16 + quad * 4]);
                bf16x8 vf;
#pragma unroll
                for (int j = 0; j < 4; j++) { vf[j] = v0[j]; vf[4 + j] = v1[j]; }
                o[0][dt] = __builtin_amdgcn_mfma_f32_16x16x32_bf16(vf, pf[0][np], o[0][dt], 0, 0, 0);
                o[1][dt] = __builtin_amdgcn_mfma_f32_16x16x32_bf16(vf, pf[1][np], o[1][dt], 0, 0, 0);
            }
    }

    float inv[2];
#pragma unroll
    for (int qt = 0; qt < 2; qt++) {
        float l = l_st[qt];
        l += __shfl_xor(l, 16);
        l += __shfl_xor(l, 32);
        inv[qt] = 1.0f / l;
    }

    // epilogue: O^T -> XOR-swizzled T (aliases Ks/Vs) -> coalesced row-major store
    __syncthreads();
#pragma unroll
    for (int qt = 0; qt < 2; qt++) {
        int row = w * 32 + qt * 16 + l15;
#pragma unroll
        for (int dt = 0; dt < 4; dt++) {
            int phys = ((dt * 2 + (quad >> 1)) ^ (l15 & 7));
            int base = row * 64 + phys * 8 + (quad & 1) * 4;
            bf16x2 t0, t1;
            t0[0] = (bf16_t)(o[qt][dt][0] * inv[qt]);
            t0[1] = (bf16_t)(o[qt][dt][1] * inv[qt]);
            t1[0] = (bf16_t)(o[qt][dt][2] * inv[qt]);
            t1[1] = (bf16_t)(o[qt][dt][3] * inv[qt]);
            *reinterpret_cast<bf16x2*>(&T[base])     = t0;
            *reinterpret_cast<bf16x2*>(&T[base + 2]) = t1;
        }
    }
    __syncthreads();
    {
        int row = w * 32 + (lane >> 1);
        int ch  = lane & 1;
        size_t orow = ((size_t)(b * S_ + qblk * 128) + row) * D_ + h * 64 + ch * 32;
#pragma unroll
        for (int k = 0; k < 4; k++) {
            int phys = (ch * 4 + k) ^ (row & 7);
            bf16x8 frag = *reinterpret_cast<const bf16x8*>(&T[row * 64 + phys * 8]);
            *reinterpret_cast<bf16x8*>(&Out[orow + k * 8]) = frag;
        }
    }
}

extern "C" void kernel_launch(void* const* d_in, const int* in_sizes, int n_in,
                              void* d_out, int out_size, void* d_ws, size_t ws_size,
                              hipStream_t stream) {
    const float* q  = (const float*)d_in[0];
    const float* k  = (const float*)d_in[1];
    const float* v  = (const float*)d_in[2];
    const int*   vl = (const int*)d_in[3];
    const float* Wq = (const float*)d_in[4];
    const float* Wk = (const float*)d_in[5];
    const float* Wv = (const float*)d_in[6];
    const float* Wo = (const float*)d_in[7];
    float* out = (float*)d_out;

    bf16_t* ws = (bf16_t*)d_ws;
    const size_t SD = (size_t)8192 * 1024;
    const size_t WW = (size_t)1024 * 1024;
    bf16_t* Qp   = ws;
    bf16_t* Kp   = ws + SD;
    bf16_t* Vt   = ws + 2 * SD;    // per-head V^T: [(b*16+h)*64+d][s]
    bf16_t* tmpO = ws + 3 * SD;    // attn output
    bf16_t* Wqb  = ws + 4 * SD;
    bf16_t* Wkb  = Wqb + WW;
    bf16_t* Wvb  = Wqb + 2 * WW;
    bf16_t* Wob  = Wqb + 3 * WW;
    // total: 4*SD + 4*WW elems = 75.5 MB

    const float cs = 0.18033688f;  // (1/8)*log2(e) baked into Q projection
    dim3 blk(256);

    cast4_f32_bf16<<<dim3(1024, 4), blk, 0, stream>>>(Wq, Wk, Wv, Wo, Wqb, Wkb, Wvb, Wob, 262144);
    gemm_qkv<<<dim3(8, 64, 3), blk, 0, stream>>>(q, k, v, Wqb, Wkb, Wvb, Qp, Kp, Vt, cs);
    attn_fused<<<dim3(16, 64), blk, 0, stream>>>(Qp, Kp, Vt, vl, tmpO);
    gemm_out<<<dim3(8, 64), blk, 0, stream>>>(tmpO, Wob, out);
}

// Round 6
// 381.107 us; speedup vs baseline: 1.2309x; 1.2309x over previous
//
#include <hip/hip_runtime.h>
#include <hip/hip_bf16.h>

using bf16_t = __bf16;
using bf16x8 = __attribute__((ext_vector_type(8))) __bf16;
using bf16x4 = __attribute__((ext_vector_type(4))) __bf16;
using bf16x2 = __attribute__((ext_vector_type(2))) __bf16;
using f32x4  = __attribute__((ext_vector_type(4))) float;

#define S_  2048
#define D_  1024

typedef __attribute__((address_space(1))) unsigned int glb_u32;
typedef __attribute__((address_space(3))) unsigned int lds_u32;

__device__ __forceinline__ void async_cp16(const void* g, void* lds) {
    __builtin_amdgcn_global_load_lds(
        (glb_u32*)(unsigned long long)g,
        (lds_u32*)(unsigned int)(unsigned long long)lds,
        16, 0, 0);
}

// ---------------- f32 -> bf16 casts ----------------
__global__ __launch_bounds__(256) void cast_f32_bf16(const float* __restrict__ s,
                                                     bf16_t* __restrict__ d, int n4) {
    int i = blockIdx.x * 256 + threadIdx.x;
    if (i >= n4) return;
    float4 f = reinterpret_cast<const float4*>(s)[i];
    bf16x4 o;
    o[0] = (bf16_t)f.x; o[1] = (bf16_t)f.y; o[2] = (bf16_t)f.z; o[3] = (bf16_t)f.w;
    reinterpret_cast<bf16x4*>(d)[i] = o;
}

__global__ __launch_bounds__(256) void cast2_f32_bf16(const float* __restrict__ a, const float* __restrict__ b,
                                                      bf16_t* __restrict__ oa, bf16_t* __restrict__ ob, int n4) {
    int i = blockIdx.x * 256 + threadIdx.x;
    if (i >= n4) return;
    const float* s = blockIdx.y ? b : a;
    bf16_t*      d = blockIdx.y ? ob : oa;
    float4 f = reinterpret_cast<const float4*>(s)[i];
    bf16x4 o;
    o[0] = (bf16_t)f.x; o[1] = (bf16_t)f.y; o[2] = (bf16_t)f.z; o[3] = (bf16_t)f.w;
    reinterpret_cast<bf16x4*>(d)[i] = o;
}

__global__ __launch_bounds__(256) void cast4_f32_bf16(const float* __restrict__ a, const float* __restrict__ b,
                                                      const float* __restrict__ c, const float* __restrict__ dd,
                                                      bf16_t* __restrict__ oa, bf16_t* __restrict__ ob,
                                                      bf16_t* __restrict__ oc, bf16_t* __restrict__ od, int n4) {
    int i = blockIdx.x * 256 + threadIdx.x;
    if (i >= n4) return;
    const float* s; bf16_t* d;
    int w = blockIdx.y;
    if      (w == 0) { s = a;  d = oa; }
    else if (w == 1) { s = b;  d = ob; }
    else if (w == 2) { s = c;  d = oc; }
    else             { s = dd; d = od; }
    float4 f = reinterpret_cast<const float4*>(s)[i];
    bf16x4 o;
    o[0] = (bf16_t)f.x; o[1] = (bf16_t)f.y; o[2] = (bf16_t)f.z; o[3] = (bf16_t)f.w;
    reinterpret_cast<bf16x4*>(d)[i] = o;
}

// ---------------- GEMM: C[M x 1024] = A[M x 1024] * Bt[1024 x 1024]^T ----------------
// 64m x 128n block tile (4 waves as 2x2, wave tile 32x64, acc 2x4).
// 12 KB LDS, ~100 VGPR -> 4-5 blocks/CU resident; grid (8, M/64) = 1024 blocks.
// MODE 0: bf16 row-major (x scale); 1: f32 row-major; 2: bf16 transposed into
//         per-head Vt[((m>>11)*16 + (n>>6))*64 + (n&63)][m&2047].
template <int MODE>
__global__ __launch_bounds__(256) void gemm64(const bf16_t* __restrict__ A,
                                              const bf16_t* __restrict__ Bt,
                                              void* __restrict__ Cv, float scale) {
    __shared__ bf16_t As[64 * 32];
    __shared__ bf16_t Bs[128 * 32];
    const int K = 1024;
    int tid  = threadIdx.x;
    int lane = tid & 63, w = tid >> 6;
    int l15  = lane & 15, quad = lane >> 4;
    int m0 = blockIdx.y * 64, n0 = blockIdx.x * 128;
    int wm = (w >> 1) * 32, wn = (w & 1) * 64;

    const bf16_t* Ag = A  + (size_t)(m0 + (tid >> 2)) * K + (tid & 3) * 8;
    const bf16_t* Bg = Bt + (size_t)(n0 + (tid >> 2)) * K + (tid & 3) * 8;
    bf16_t* Asw = As + tid * 8;
    bf16_t* Bsw = Bs + tid * 8;

    f32x4 acc[2][4] = {};

    for (int k0 = 0; k0 < K; k0 += 32) {
        __syncthreads();
        async_cp16(Ag + k0,                    Asw);
        async_cp16(Bg + k0,                    Bsw);
        async_cp16(Bg + k0 + (size_t)64 * K,   Bsw + 2048);
        __syncthreads();
        bf16x8 af[2], bfr[4];
#pragma unroll
        for (int t = 0; t < 2; t++)
            af[t]  = *reinterpret_cast<const bf16x8*>(&As[(wm + t * 16 + l15) * 32 + quad * 8]);
#pragma unroll
        for (int t = 0; t < 4; t++)
            bfr[t] = *reinterpret_cast<const bf16x8*>(&Bs[(wn + t * 16 + l15) * 32 + quad * 8]);
#pragma unroll
        for (int mt = 0; mt < 2; mt++)
#pragma unroll
            for (int nt = 0; nt < 4; nt++)
                acc[mt][nt] = __builtin_amdgcn_mfma_f32_16x16x32_bf16(af[mt], bfr[nt], acc[mt][nt], 0, 0, 0);
    }

#pragma unroll
    for (int mt = 0; mt < 2; mt++)
#pragma unroll
        for (int nt = 0; nt < 4; nt++) {
            if (MODE == 2) {
                int m = m0 + wm + mt * 16 + quad * 4;
                int n = n0 + wn + nt * 16 + l15;
                bf16x4 o4;
#pragma unroll
                for (int r = 0; r < 4; r++) o4[r] = (bf16_t)(acc[mt][nt][r] * scale);
                size_t vrow = (size_t)((m >> 11) * 16 + (n >> 6)) * 64 + (n & 63);
                *reinterpret_cast<bf16x4*>(&((bf16_t*)Cv)[vrow * S_ + (m & 2047)]) = o4;
            } else {
#pragma unroll
                for (int r = 0; r < 4; r++) {
                    int m = m0 + wm + mt * 16 + quad * 4 + r;
                    int n = n0 + wn + nt * 16 + l15;
                    size_t idx = (size_t)m * 1024 + n;
                    if (MODE == 1) reinterpret_cast<float*>(Cv)[idx] = acc[mt][nt][r] * scale;
                    else           reinterpret_cast<bf16_t*>(Cv)[idx] = (bf16_t)(acc[mt][nt][r] * scale);
                }
            }
        }
}

// ---------------- fused masked attention (R4-proven version) ----------------
// Transposed-S: St = K Q^T feeds O^T = V^T P^T straight from registers.
// Max-free exp2 softmax; Q pre-scaled by (1/8)log2(e) in its projection GEMM.
__global__ __launch_bounds__(256) void attn_fused(const bf16_t* __restrict__ Qp,
                                                  const bf16_t* __restrict__ Kp,
                                                  const bf16_t* __restrict__ Vt,
                                                  const int* __restrict__ vlen_p,
                                                  bf16_t* __restrict__ Out) {
    __shared__ bf16_t Qs[2 * 128 * 32];   // [kk][row][32]; reused as T[128][64] in epilogue
    __shared__ bf16_t Ks[2 * 64 * 32];    // [kk][row][32]
    __shared__ bf16_t Vs[64 * 68];        // [d][s], stride 68 -> conflict-free b64 reads

    int tid  = threadIdx.x;
    int lane = tid & 63, w = tid >> 6;
    int l15  = lane & 15, quad = lane >> 4;
    int qblk = blockIdx.x;
    int bh = blockIdx.y, b = bh >> 4, h = bh & 15;
    int vlen = vlen_p[b];
    int nkb  = (vlen + 63) >> 6;

    const bf16_t* Qg = Qp + (size_t)(b * S_ + qblk * 128) * D_ + h * 64;
    const bf16_t* Kg = Kp + (size_t)b * S_ * D_ + h * 64;
    const bf16_t* Vg = Vt + (size_t)bh * 64 * S_;

#pragma unroll
    for (int j = 0; j < 4; j++) {
        int linear = j * 256 + tid;
        int kk = linear >> 9, row = (linear >> 2) & 127, sub = linear & 3;
        async_cp16(Qg + (size_t)row * D_ + kk * 32 + sub * 8, Qs + linear * 8);
    }
    __syncthreads();
    bf16x8 qf[2][2];
#pragma unroll
    for (int qt = 0; qt < 2; qt++)
#pragma unroll
        for (int kk = 0; kk < 2; kk++)
            qf[qt][kk] = *reinterpret_cast<const bf16x8*>(&Qs[kk * 4096 + (w * 32 + qt * 16 + l15) * 32 + quad * 8]);

    f32x4 o[2][4] = {};
    float l_st[2] = {0.f, 0.f};

    for (int kb = 0; kb < nkb; kb++) {
        __syncthreads();
#pragma unroll
        for (int j = 0; j < 2; j++) {
            int linear = j * 256 + tid;
            int kk = linear >> 8, row = (linear >> 2) & 63, sub = linear & 3;
            async_cp16(Kg + (size_t)(kb * 64 + row) * D_ + kk * 32 + sub * 8, Ks + linear * 8);
        }
#pragma unroll
        for (int j = 0; j < 2; j++) {
            int linear = j * 256 + tid;
            int row = linear >> 3, c8 = linear & 7;
            uint4 vv = *reinterpret_cast<const uint4*>(&Vg[(size_t)row * S_ + kb * 64 + c8 * 8]);
            uint2* vp = reinterpret_cast<uint2*>(&Vs[row * 68 + c8 * 8]);
            vp[0] = make_uint2(vv.x, vv.y);
            vp[1] = make_uint2(vv.z, vv.w);
        }
        __syncthreads();

        // St = K Q^T, both q-tiles sharing K fragments
        f32x4 sc[2][4] = {};
#pragma unroll
        for (int nt = 0; nt < 4; nt++)
#pragma unroll
            for (int kk = 0; kk < 2; kk++) {
                bf16x8 kf = *reinterpret_cast<const bf16x8*>(&Ks[kk * 2048 + (nt * 16 + l15) * 32 + quad * 8]);
                sc[0][nt] = __builtin_amdgcn_mfma_f32_16x16x32_bf16(kf, qf[0][kk], sc[0][nt], 0, 0, 0);
                sc[1][nt] = __builtin_amdgcn_mfma_f32_16x16x32_bf16(kf, qf[1][kk], sc[1][nt], 0, 0, 0);
            }

        // max-free softmax: p = exp2(st) (scale baked into Q); per-lane l accumulation
        bool partial = (vlen & 63) && (kb == nkb - 1);
        bf16x8 pf[2][2];
        if (!partial) {
#pragma unroll
            for (int qt = 0; qt < 2; qt++) {
                float lacc = 0.f;
#pragma unroll
                for (int nt = 0; nt < 4; nt++)
#pragma unroll
                    for (int r = 0; r < 4; r++) {
                        float p = __builtin_exp2f(sc[qt][nt][r]);
                        lacc += p;
                        pf[qt][nt >> 1][(nt & 1) * 4 + r] = (bf16_t)p;
                    }
                l_st[qt] += lacc;
            }
        } else {
#pragma unroll
            for (int qt = 0; qt < 2; qt++) {
                float lacc = 0.f;
#pragma unroll
                for (int nt = 0; nt < 4; nt++)
#pragma unroll
                    for (int r = 0; r < 4; r++) {
                        float p = __builtin_exp2f(sc[qt][nt][r]);
                        if (kb * 64 + nt * 16 + quad * 4 + r >= vlen) p = 0.f;
                        lacc += p;
                        pf[qt][nt >> 1][(nt & 1) * 4 + r] = (bf16_t)p;
                    }
                l_st[qt] += lacc;
            }
        }

        // O^T += V^T P^T ; V^T A-fragments via conflict-free b64 pairs
#pragma unroll
        for (int np = 0; np < 2; np++)
#pragma unroll
            for (int dt = 0; dt < 4; dt++) {
                bf16x4 v0 = *reinterpret_cast<const bf16x4*>(&Vs[(dt * 16 + l15) * 68 + np * 32 + quad * 4]);
                bf16x4 v1 = *reinterpret_cast<const bf16x4*>(&Vs[(dt * 16 + l15) * 68 + np * 32 + 16 + quad * 4]);
                bf16x8 vf;
#pragma unroll
                for (int j = 0; j < 4; j++) { vf[j] = v0[j]; vf[4 + j] = v1[j]; }
                o[0][dt] = __builtin_amdgcn_mfma_f32_16x16x32_bf16(vf, pf[0][np], o[0][dt], 0, 0, 0);
                o[1][dt] = __builtin_amdgcn_mfma_f32_16x16x32_bf16(vf, pf[1][np], o[1][dt], 0, 0, 0);
            }
    }

    float inv[2];
#pragma unroll
    for (int qt = 0; qt < 2; qt++) {
        float l = l_st[qt];
        l += __shfl_xor(l, 16);
        l += __shfl_xor(l, 32);
        inv[qt] = 1.0f / l;
    }

    // epilogue: O^T -> XOR-swizzled LDS (reuse Qs) -> coalesced row-major store
    __syncthreads();
    bf16_t* T = Qs;
#pragma unroll
    for (int qt = 0; qt < 2; qt++) {
        int row = w * 32 + qt * 16 + l15;
#pragma unroll
        for (int dt = 0; dt < 4; dt++) {
            int phys = ((dt * 2 + (quad >> 1)) ^ (l15 & 7));
            int base = row * 64 + phys * 8 + (quad & 1) * 4;
            bf16x2 t0, t1;
            t0[0] = (bf16_t)(o[qt][dt][0] * inv[qt]);
            t0[1] = (bf16_t)(o[qt][dt][1] * inv[qt]);
            t1[0] = (bf16_t)(o[qt][dt][2] * inv[qt]);
            t1[1] = (bf16_t)(o[qt][dt][3] * inv[qt]);
            *reinterpret_cast<bf16x2*>(&T[base])     = t0;
            *reinterpret_cast<bf16x2*>(&T[base + 2]) = t1;
        }
    }
    __syncthreads();
    {
        int row = w * 32 + (lane >> 1);
        int ch  = lane & 1;
        size_t orow = ((size_t)(b * S_ + qblk * 128) + row) * D_ + h * 64 + ch * 32;
#pragma unroll
        for (int k = 0; k < 4; k++) {
            int phys = (ch * 4 + k) ^ (row & 7);
            bf16x8 frag = *reinterpret_cast<const bf16x8*>(&T[row * 64 + phys * 8]);
            *reinterpret_cast<bf16x8*>(&Out[orow + k * 8]) = frag;
        }
    }
}

extern "C" void kernel_launch(void* const* d_in, const int* in_sizes, int n_in,
                              void* d_out, int out_size, void* d_ws, size_t ws_size,
                              hipStream_t stream) {
    const float* q  = (const float*)d_in[0];
    const float* k  = (const float*)d_in[1];
    const float* v  = (const float*)d_in[2];
    const int*   vl = (const int*)d_in[3];
    const float* Wq = (const float*)d_in[4];
    const float* Wk = (const float*)d_in[5];
    const float* Wv = (const float*)d_in[6];
    const float* Wo = (const float*)d_in[7];
    float* out = (float*)d_out;

    bf16_t* ws = (bf16_t*)d_ws;
    const size_t SD = (size_t)8192 * 1024;
    const size_t WW = (size_t)1024 * 1024;
    bf16_t* tmpA = ws;             // q bf16, then v bf16
    bf16_t* tmpB = ws + SD;        // k bf16, then attn output
    bf16_t* Qp   = ws + 2 * SD;
    bf16_t* Kp   = ws + 3 * SD;
    bf16_t* Vt   = ws + 4 * SD;    // per-head V^T: [(b*16+h)*64+d][s]
    bf16_t* Wqb  = ws + 5 * SD;
    bf16_t* Wkb  = Wqb + WW;
    bf16_t* Wvb  = Wqb + 2 * WW;
    bf16_t* Wob  = Wqb + 3 * WW;
    // total: 5*SD + 4*WW elems = 88.1 MB (within known-good 92.3 MB footprint)

    const float cs = 0.18033688f;  // (1/8)*log2(e) baked into Q projection
    dim3 blk(256);
    dim3 gg(8, 128);               // n-tiles x m-tiles, 1024 blocks

    cast4_f32_bf16<<<dim3(1024, 4), blk, 0, stream>>>(Wq, Wk, Wv, Wo, Wqb, Wkb, Wvb, Wob, 262144);
    cast2_f32_bf16<<<dim3(8192, 2), blk, 0, stream>>>(q, k, tmpA, tmpB, 2097152);

    gemm64<0><<<gg, blk, 0, stream>>>(tmpA, Wqb, Qp, cs);
    gemm64<0><<<gg, blk, 0, stream>>>(tmpB, Wkb, Kp, 1.0f);
    cast_f32_bf16<<<dim3(8192), blk, 0, stream>>>(v, tmpA, 2097152);
    gemm64<2><<<gg, blk, 0, stream>>>(tmpA, Wvb, Vt, 1.0f);

    attn_fused<<<dim3(16, 64), blk, 0, stream>>>(Qp, Kp, Vt, vl, tmpB);
    gemm64<1><<<gg, blk, 0, stream>>>(tmpB, Wob, out, 1.0f);
}